// Round 1
// baseline (265.386 us; speedup 1.0000x reference)
//
#include <hip/hip_runtime.h>

// One thread = one batch row. All state in registers, statically indexed.
// Weights are uniform (same address across lanes, compile-time offsets) ->
// compiler emits scalar loads into SGPRs; v_fmac_f32 takes 1 SGPR operand free.

__device__ __forceinline__ float fexp2(float x) { return __builtin_amdgcn_exp2f(x); }
__device__ __forceinline__ float frcp(float x)  { return __builtin_amdgcn_rcpf(x); }

// sigmoid(x) = 1/(1+2^(-x*log2(e))); saturates correctly at +-inf
__device__ __forceinline__ float sigmoid_f(float x) {
    return frcp(1.0f + fexp2(-1.44269504088896f * x));
}
// tanh(x) = 1 - 2/(1+2^(x*2*log2(e))); saturates correctly at +-inf
__device__ __forceinline__ float tanh_f(float x) {
    float e = fexp2(2.88539008177793f * x);
    return 1.0f - 2.0f * frcp(1.0f + e);
}

__global__ __launch_bounds__(256) void aggreg_policy_kernel(
    const float* __restrict__ x,
    const float* __restrict__ Wj,    const float* __restrict__ bj,
    const float* __restrict__ Wm,    const float* __restrict__ bm,
    const float* __restrict__ Wih_j, const float* __restrict__ Whh_j,
    const float* __restrict__ bih_j, const float* __restrict__ bhh_j,
    const float* __restrict__ Wih_m, const float* __restrict__ Whh_m,
    const float* __restrict__ bih_m, const float* __restrict__ bhh_m,
    const float* __restrict__ Wa,    const float* __restrict__ ba,
    float* __restrict__ out, int nrows)
{
    int b = blockIdx.x * blockDim.x + threadIdx.x;
    if (b >= nrows) return;

    const float* xr = x + (long)b * 18;
    float obs[4], jv[7], jd[7];
    #pragma unroll
    for (int i = 0; i < 4; ++i) obs[i] = xr[i];
    #pragma unroll
    for (int i = 0; i < 7; ++i) jv[i] = xr[4 + i];
    #pragma unroll
    for (int i = 0; i < 7; ++i) jd[i] = xr[11 + i];

    float hj[7][4], hm[4];
    #pragma unroll
    for (int k = 0; k < 7; ++k)
        #pragma unroll
        for (int u = 0; u < 4; ++u)
            hj[k][u] = fmaf(Wj[u * 2 + 0], jv[k], fmaf(Wj[u * 2 + 1], jd[k], bj[u]));
    #pragma unroll
    for (int u = 0; u < 4; ++u) {
        float a = bm[u];
        #pragma unroll
        for (int v = 0; v < 4; ++v) a = fmaf(Wm[u * 4 + v], obs[v], a);
        hm[u] = a;
    }

    // fold r,z biases (bih+bhh) once; n-gate biases must stay separate
    float bmrz[8], bjrz[8];
    #pragma unroll
    for (int g = 0; g < 8; ++g) {
        bmrz[g] = bih_m[g] + bhh_m[g];
        bjrz[g] = bih_j[g] + bhh_j[g];
    }

    #pragma unroll 1   // keep code size ~1 iteration (I$), trip count 7
    for (int it = 0; it < 7; ++it) {
        // ---- m-GRU: input = hj[0], hidden = hm (uses OLD hj, OLD hm) ----
        float hmn[4];
        {
            float pre_rz[8], inn[4], hn[4];
            #pragma unroll
            for (int g = 0; g < 8; ++g) {
                float a = bmrz[g];
                #pragma unroll
                for (int v = 0; v < 4; ++v) a = fmaf(Wih_m[g * 4 + v], hj[0][v], a);
                #pragma unroll
                for (int v = 0; v < 4; ++v) a = fmaf(Whh_m[g * 4 + v], hm[v], a);
                pre_rz[g] = a;
            }
            #pragma unroll
            for (int u = 0; u < 4; ++u) {
                float a = bih_m[8 + u];
                #pragma unroll
                for (int v = 0; v < 4; ++v) a = fmaf(Wih_m[(8 + u) * 4 + v], hj[0][v], a);
                inn[u] = a;
                float c = bhh_m[8 + u];
                #pragma unroll
                for (int v = 0; v < 4; ++v) c = fmaf(Whh_m[(8 + u) * 4 + v], hm[v], c);
                hn[u] = c;
            }
            #pragma unroll
            for (int u = 0; u < 4; ++u) {
                float r = sigmoid_f(pre_rz[u]);
                float z = sigmoid_f(pre_rz[4 + u]);
                float n = tanh_f(fmaf(r, hn[u], inn[u]));
                hmn[u] = fmaf(z, hm[u] - n, n);   // (1-z)*n + z*h
            }
        }

        // ---- j-GRU over 7 nodes: inp = [left, right], hidden = hj[k] ----
        float nh[7][4];
        #pragma unroll
        for (int k = 0; k < 7; ++k) {
            float L[4], R[4];
            #pragma unroll
            for (int u = 0; u < 4; ++u) {
                L[u] = (k == 0) ? hm[u] : hj[k - 1][u];   // OLD hm
                R[u] = (k == 6) ? 0.0f  : hj[k + 1][u];
            }
            float pre_rz[8], inn[4], hn[4];
            #pragma unroll
            for (int g = 0; g < 8; ++g) {
                float a = bjrz[g];
                #pragma unroll
                for (int v = 0; v < 4; ++v) a = fmaf(Wih_j[g * 8 + v],     L[v], a);
                #pragma unroll
                for (int v = 0; v < 4; ++v) a = fmaf(Wih_j[g * 8 + 4 + v], R[v], a);
                #pragma unroll
                for (int v = 0; v < 4; ++v) a = fmaf(Whh_j[g * 4 + v], hj[k][v], a);
                pre_rz[g] = a;
            }
            #pragma unroll
            for (int u = 0; u < 4; ++u) {
                float a = bih_j[8 + u];
                #pragma unroll
                for (int v = 0; v < 4; ++v) a = fmaf(Wih_j[(8 + u) * 8 + v],     L[v], a);
                #pragma unroll
                for (int v = 0; v < 4; ++v) a = fmaf(Wih_j[(8 + u) * 8 + 4 + v], R[v], a);
                inn[u] = a;
                float c = bhh_j[8 + u];
                #pragma unroll
                for (int v = 0; v < 4; ++v) c = fmaf(Whh_j[(8 + u) * 4 + v], hj[k][v], c);
                hn[u] = c;
            }
            #pragma unroll
            for (int u = 0; u < 4; ++u) {
                float r = sigmoid_f(pre_rz[u]);
                float z = sigmoid_f(pre_rz[4 + u]);
                float n = tanh_f(fmaf(r, hn[u], inn[u]));
                nh[k][u] = fmaf(z, hj[k][u] - n, n);
            }
        }

        #pragma unroll
        for (int k = 0; k < 7; ++k)
            #pragma unroll
            for (int u = 0; u < 4; ++u) hj[k][u] = nh[k][u];
        #pragma unroll
        for (int u = 0; u < 4; ++u) hm[u] = hmn[u];
    }

    float* orow = out + (long)b * 7;
    #pragma unroll
    for (int k = 0; k < 7; ++k) {
        float a = ba[0];
        #pragma unroll
        for (int u = 0; u < 4; ++u) a = fmaf(Wa[u], hj[k][u], a);
        orow[k] = a;
    }
}

extern "C" void kernel_launch(void* const* d_in, const int* in_sizes, int n_in,
                              void* d_out, int out_size, void* d_ws, size_t ws_size,
                              hipStream_t stream) {
    const float* x     = (const float*)d_in[0];
    const float* Wj    = (const float*)d_in[1];
    const float* bj    = (const float*)d_in[2];
    const float* Wm    = (const float*)d_in[3];
    const float* bm    = (const float*)d_in[4];
    const float* Wih_j = (const float*)d_in[5];
    const float* Whh_j = (const float*)d_in[6];
    const float* bih_j = (const float*)d_in[7];
    const float* bhh_j = (const float*)d_in[8];
    const float* Wih_m = (const float*)d_in[9];
    const float* Whh_m = (const float*)d_in[10];
    const float* bih_m = (const float*)d_in[11];
    const float* bhh_m = (const float*)d_in[12];
    const float* Wa    = (const float*)d_in[13];
    const float* ba    = (const float*)d_in[14];
    float* out = (float*)d_out;

    int nrows = in_sizes[0] / 18;
    int block = 256;
    int grid = (nrows + block - 1) / block;
    aggreg_policy_kernel<<<grid, block, 0, stream>>>(
        x, Wj, bj, Wm, bm, Wih_j, Whh_j, bih_j, bhh_j,
        Wih_m, Whh_m, bih_m, bhh_m, Wa, ba, out, nrows);
}

// Round 2
// 238.714 us; speedup vs baseline: 1.1117x; 1.1117x over previous
//
#include <hip/hip_runtime.h>

// Strategy: one thread = one row, all state in registers, statically indexed.
// A one-block pack kernel pre-scales weights into d_ws so sigmoid/tanh lose
// their input muls, and pre-sums r/z biases. Main kernel gets VGPR headroom
// via __launch_bounds__(256,4) (cap 128) -- round 1's 44-VGPR squeeze caused
// remat/shuffle overhead (measured ~1.5x issue-cycle inflation).

__device__ __forceinline__ float fexp2(float x) { return __builtin_amdgcn_exp2f(x); }
__device__ __forceinline__ float frcp(float x)  { return __builtin_amdgcn_rcpf(x); }

// ---- packed weight layout (floats) ----
#define O_AIHJ 0     // [12][8] Wih_j, rows 0-7 * -log2e, rows 8-11 * 2log2e
#define O_AHHJ 96    // [12][4] Whh_j, same row scaling
#define O_BRZJ 144   // [8]  (bih_j+bhh_j)[0:8] * -log2e
#define O_BINJ 152   // [4]  bih_j[8:12] * 2log2e
#define O_BHNJ 156   // [4]  bhh_j[8:12] * 2log2e
#define O_AIHM 160   // [12][4] Wih_m scaled
#define O_AHHM 208   // [12][4] Whh_m scaled
#define O_BRZM 256   // [8]
#define O_BINM 264   // [4]
#define O_BHNM 268   // [4]
#define O_WJ   272   // [4][2]
#define O_BJ   280   // [4]
#define O_WM   284   // [4][4]
#define O_BM   300   // [4]
#define O_WA   304   // [4]
#define O_BA   308   // [1]
#define W_TOT  309

__global__ void pack_weights_kernel(
    const float* __restrict__ Wj,    const float* __restrict__ bj,
    const float* __restrict__ Wm,    const float* __restrict__ bm,
    const float* __restrict__ Wih_j, const float* __restrict__ Whh_j,
    const float* __restrict__ bih_j, const float* __restrict__ bhh_j,
    const float* __restrict__ Wih_m, const float* __restrict__ Whh_m,
    const float* __restrict__ bih_m, const float* __restrict__ bhh_m,
    const float* __restrict__ Wa,    const float* __restrict__ ba,
    float* __restrict__ ws)
{
    int t = threadIdx.x;                      // one block of 512
    const float SN = -1.44269504088896f;      // sigmoid: exp2(SN*x) = e^-x
    const float ST =  2.88539008177793f;      // tanh:    exp2(ST*x) = e^(2x)
    if (t < 96)       { int g = t >> 3;            ws[t] = Wih_j[t] * (g < 8 ? SN : ST); }
    else if (t < 144) { int i = t - 96;  int g = i >> 2; ws[t] = Whh_j[i] * (g < 8 ? SN : ST); }
    else if (t < 152) { int g = t - 144;           ws[t] = (bih_j[g] + bhh_j[g]) * SN; }
    else if (t < 156) { int u = t - 152;           ws[t] = bih_j[8 + u] * ST; }
    else if (t < 160) { int u = t - 156;           ws[t] = bhh_j[8 + u] * ST; }
    else if (t < 208) { int i = t - 160; int g = i >> 2; ws[t] = Wih_m[i] * (g < 8 ? SN : ST); }
    else if (t < 256) { int i = t - 208; int g = i >> 2; ws[t] = Whh_m[i] * (g < 8 ? SN : ST); }
    else if (t < 264) { int g = t - 256;           ws[t] = (bih_m[g] + bhh_m[g]) * SN; }
    else if (t < 268) { int u = t - 264;           ws[t] = bih_m[8 + u] * ST; }
    else if (t < 272) { int u = t - 268;           ws[t] = bhh_m[8 + u] * ST; }
    else if (t < 280) { ws[t] = Wj[t - 272]; }
    else if (t < 284) { ws[t] = bj[t - 280]; }
    else if (t < 300) { ws[t] = Wm[t - 284]; }
    else if (t < 304) { ws[t] = bm[t - 300]; }
    else if (t < 308) { ws[t] = Wa[t - 304]; }
    else if (t < 309) { ws[t] = ba[0]; }
}

__global__ __launch_bounds__(256, 4) void aggreg_policy_packed(
    const float* __restrict__ x, const float* __restrict__ W,
    float* __restrict__ out, int nrows)
{
    int b = blockIdx.x * blockDim.x + threadIdx.x;
    if (b >= nrows) return;

    // 18 floats per row; row stride 72B -> 8B aligned for every b: float2 loads
    const float2* xr2 = (const float2*)(x + (long)b * 18);
    float xin[18];
    #pragma unroll
    for (int i = 0; i < 9; ++i) { float2 v = xr2[i]; xin[2*i] = v.x; xin[2*i+1] = v.y; }

    float hj[7][4], hm[4];
    #pragma unroll
    for (int k = 0; k < 7; ++k)
        #pragma unroll
        for (int u = 0; u < 4; ++u)
            hj[k][u] = fmaf(W[O_WJ + u*2 + 0], xin[4 + k],
                       fmaf(W[O_WJ + u*2 + 1], xin[11 + k], W[O_BJ + u]));
    #pragma unroll
    for (int u = 0; u < 4; ++u) {
        float a = W[O_BM + u];
        #pragma unroll
        for (int v = 0; v < 4; ++v) a = fmaf(W[O_WM + u*4 + v], xin[v], a);
        hm[u] = a;
    }

    #pragma unroll 1   // code size: keep one iteration resident in I$
    for (int it = 0; it < 7; ++it) {
        // ---- m-GRU: input hj[0], hidden hm (both OLD) ----
        float hmn[4];
        {
            float pre[8], inn[4], hn[4];
            #pragma unroll
            for (int g = 0; g < 8; ++g) {
                float a = W[O_BRZM + g];
                #pragma unroll
                for (int v = 0; v < 4; ++v) a = fmaf(W[O_AIHM + g*4 + v], hj[0][v], a);
                #pragma unroll
                for (int v = 0; v < 4; ++v) a = fmaf(W[O_AHHM + g*4 + v], hm[v], a);
                pre[g] = a;
            }
            #pragma unroll
            for (int u = 0; u < 4; ++u) {
                float a = W[O_BINM + u];
                #pragma unroll
                for (int v = 0; v < 4; ++v) a = fmaf(W[O_AIHM + (8+u)*4 + v], hj[0][v], a);
                inn[u] = a;
                float c = W[O_BHNM + u];
                #pragma unroll
                for (int v = 0; v < 4; ++v) c = fmaf(W[O_AHHM + (8+u)*4 + v], hm[v], c);
                hn[u] = c;
            }
            #pragma unroll
            for (int u = 0; u < 4; ++u) {
                float r = frcp(1.0f + fexp2(pre[u]));        // pre already * -log2e
                float z = frcp(1.0f + fexp2(pre[4 + u]));
                float narg = fmaf(r, hn[u], inn[u]);         // already * 2log2e
                float n = fmaf(-2.0f, frcp(1.0f + fexp2(narg)), 1.0f);
                hmn[u] = fmaf(z, hm[u] - n, n);
            }
        }

        // ---- j-GRU over 7 nodes (all read OLD hj / OLD hm) ----
        float nh[7][4];
        #pragma unroll
        for (int k = 0; k < 7; ++k) {
            float L[4];
            #pragma unroll
            for (int u = 0; u < 4; ++u) L[u] = (k == 0) ? hm[u] : hj[k-1][u];

            float pre[8], inn[4], hn[4];
            #pragma unroll
            for (int g = 0; g < 8; ++g) {
                float a = W[O_BRZJ + g];
                #pragma unroll
                for (int v = 0; v < 4; ++v) a = fmaf(W[O_AIHJ + g*8 + v], L[v], a);
                if (k != 6) {       // k==6: right neighbor is zero-pad -> skip 48 FMAs
                    #pragma unroll
                    for (int v = 0; v < 4; ++v) a = fmaf(W[O_AIHJ + g*8 + 4 + v], hj[k+1][v], a);
                }
                #pragma unroll
                for (int v = 0; v < 4; ++v) a = fmaf(W[O_AHHJ + g*4 + v], hj[k][v], a);
                pre[g] = a;
            }
            #pragma unroll
            for (int u = 0; u < 4; ++u) {
                float a = W[O_BINJ + u];
                #pragma unroll
                for (int v = 0; v < 4; ++v) a = fmaf(W[O_AIHJ + (8+u)*8 + v], L[v], a);
                if (k != 6) {
                    #pragma unroll
                    for (int v = 0; v < 4; ++v) a = fmaf(W[O_AIHJ + (8+u)*8 + 4 + v], hj[k+1][v], a);
                }
                inn[u] = a;
                float c = W[O_BHNJ + u];
                #pragma unroll
                for (int v = 0; v < 4; ++v) c = fmaf(W[O_AHHJ + (8+u)*4 + v], hj[k][v], c);
                hn[u] = c;
            }
            #pragma unroll
            for (int u = 0; u < 4; ++u) {
                float r = frcp(1.0f + fexp2(pre[u]));
                float z = frcp(1.0f + fexp2(pre[4 + u]));
                float narg = fmaf(r, hn[u], inn[u]);
                float n = fmaf(-2.0f, frcp(1.0f + fexp2(narg)), 1.0f);
                nh[k][u] = fmaf(z, hj[k][u] - n, n);
            }
        }

        #pragma unroll
        for (int k = 0; k < 7; ++k)
            #pragma unroll
            for (int u = 0; u < 4; ++u) hj[k][u] = nh[k][u];
        #pragma unroll
        for (int u = 0; u < 4; ++u) hm[u] = hmn[u];
    }

    float* orow = out + (long)b * 7;
    #pragma unroll
    for (int k = 0; k < 7; ++k) {
        float a = W[O_BA];
        #pragma unroll
        for (int u = 0; u < 4; ++u) a = fmaf(W[O_WA + u], hj[k][u], a);
        orow[k] = a;
    }
}

// ---------------- round-1 fallback (used only if ws too small) ----------------
__device__ __forceinline__ float sigmoid_f(float x) {
    return frcp(1.0f + fexp2(-1.44269504088896f * x));
}
__device__ __forceinline__ float tanh_f(float x) {
    float e = fexp2(2.88539008177793f * x);
    return 1.0f - 2.0f * frcp(1.0f + e);
}

__global__ __launch_bounds__(256) void aggreg_policy_fallback(
    const float* __restrict__ x,
    const float* __restrict__ Wj,    const float* __restrict__ bj,
    const float* __restrict__ Wm,    const float* __restrict__ bm,
    const float* __restrict__ Wih_j, const float* __restrict__ Whh_j,
    const float* __restrict__ bih_j, const float* __restrict__ bhh_j,
    const float* __restrict__ Wih_m, const float* __restrict__ Whh_m,
    const float* __restrict__ bih_m, const float* __restrict__ bhh_m,
    const float* __restrict__ Wa,    const float* __restrict__ ba,
    float* __restrict__ out, int nrows)
{
    int b = blockIdx.x * blockDim.x + threadIdx.x;
    if (b >= nrows) return;
    const float* xr = x + (long)b * 18;
    float obs[4], jv[7], jd[7];
    #pragma unroll
    for (int i = 0; i < 4; ++i) obs[i] = xr[i];
    #pragma unroll
    for (int i = 0; i < 7; ++i) jv[i] = xr[4 + i];
    #pragma unroll
    for (int i = 0; i < 7; ++i) jd[i] = xr[11 + i];
    float hj[7][4], hm[4];
    #pragma unroll
    for (int k = 0; k < 7; ++k)
        #pragma unroll
        for (int u = 0; u < 4; ++u)
            hj[k][u] = fmaf(Wj[u*2], jv[k], fmaf(Wj[u*2+1], jd[k], bj[u]));
    #pragma unroll
    for (int u = 0; u < 4; ++u) {
        float a = bm[u];
        #pragma unroll
        for (int v = 0; v < 4; ++v) a = fmaf(Wm[u*4+v], obs[v], a);
        hm[u] = a;
    }
    float bmrz[8], bjrz[8];
    #pragma unroll
    for (int g = 0; g < 8; ++g) { bmrz[g] = bih_m[g]+bhh_m[g]; bjrz[g] = bih_j[g]+bhh_j[g]; }
    #pragma unroll 1
    for (int it = 0; it < 7; ++it) {
        float hmn[4];
        {
            float pre[8], inn[4], hn[4];
            #pragma unroll
            for (int g = 0; g < 8; ++g) {
                float a = bmrz[g];
                #pragma unroll
                for (int v = 0; v < 4; ++v) a = fmaf(Wih_m[g*4+v], hj[0][v], a);
                #pragma unroll
                for (int v = 0; v < 4; ++v) a = fmaf(Whh_m[g*4+v], hm[v], a);
                pre[g] = a;
            }
            #pragma unroll
            for (int u = 0; u < 4; ++u) {
                float a = bih_m[8+u];
                #pragma unroll
                for (int v = 0; v < 4; ++v) a = fmaf(Wih_m[(8+u)*4+v], hj[0][v], a);
                inn[u] = a;
                float c = bhh_m[8+u];
                #pragma unroll
                for (int v = 0; v < 4; ++v) c = fmaf(Whh_m[(8+u)*4+v], hm[v], c);
                hn[u] = c;
            }
            #pragma unroll
            for (int u = 0; u < 4; ++u) {
                float r = sigmoid_f(pre[u]);
                float z = sigmoid_f(pre[4+u]);
                float n = tanh_f(fmaf(r, hn[u], inn[u]));
                hmn[u] = fmaf(z, hm[u]-n, n);
            }
        }
        float nh[7][4];
        #pragma unroll
        for (int k = 0; k < 7; ++k) {
            float L[4], R[4];
            #pragma unroll
            for (int u = 0; u < 4; ++u) {
                L[u] = (k == 0) ? hm[u] : hj[k-1][u];
                R[u] = (k == 6) ? 0.0f  : hj[k+1][u];
            }
            float pre[8], inn[4], hn[4];
            #pragma unroll
            for (int g = 0; g < 8; ++g) {
                float a = bjrz[g];
                #pragma unroll
                for (int v = 0; v < 4; ++v) a = fmaf(Wih_j[g*8+v], L[v], a);
                #pragma unroll
                for (int v = 0; v < 4; ++v) a = fmaf(Wih_j[g*8+4+v], R[v], a);
                #pragma unroll
                for (int v = 0; v < 4; ++v) a = fmaf(Whh_j[g*4+v], hj[k][v], a);
                pre[g] = a;
            }
            #pragma unroll
            for (int u = 0; u < 4; ++u) {
                float a = bih_j[8+u];
                #pragma unroll
                for (int v = 0; v < 4; ++v) a = fmaf(Wih_j[(8+u)*8+v], L[v], a);
                #pragma unroll
                for (int v = 0; v < 4; ++v) a = fmaf(Wih_j[(8+u)*8+4+v], R[v], a);
                inn[u] = a;
                float c = bhh_j[8+u];
                #pragma unroll
                for (int v = 0; v < 4; ++v) c = fmaf(Whh_j[(8+u)*4+v], hj[k][v], c);
                hn[u] = c;
            }
            #pragma unroll
            for (int u = 0; u < 4; ++u) {
                float r = sigmoid_f(pre[u]);
                float z = sigmoid_f(pre[4+u]);
                float n = tanh_f(fmaf(r, hn[u], inn[u]));
                nh[k][u] = fmaf(z, hj[k][u]-n, n);
            }
        }
        #pragma unroll
        for (int k = 0; k < 7; ++k)
            #pragma unroll
            for (int u = 0; u < 4; ++u) hj[k][u] = nh[k][u];
        #pragma unroll
        for (int u = 0; u < 4; ++u) hm[u] = hmn[u];
    }
    float* orow = out + (long)b * 7;
    #pragma unroll
    for (int k = 0; k < 7; ++k) {
        float a = ba[0];
        #pragma unroll
        for (int u = 0; u < 4; ++u) a = fmaf(Wa[u], hj[k][u], a);
        orow[k] = a;
    }
}

extern "C" void kernel_launch(void* const* d_in, const int* in_sizes, int n_in,
                              void* d_out, int out_size, void* d_ws, size_t ws_size,
                              hipStream_t stream) {
    const float* x     = (const float*)d_in[0];
    const float* Wj    = (const float*)d_in[1];
    const float* bj    = (const float*)d_in[2];
    const float* Wm    = (const float*)d_in[3];
    const float* bm    = (const float*)d_in[4];
    const float* Wih_j = (const float*)d_in[5];
    const float* Whh_j = (const float*)d_in[6];
    const float* bih_j = (const float*)d_in[7];
    const float* bhh_j = (const float*)d_in[8];
    const float* Wih_m = (const float*)d_in[9];
    const float* Whh_m = (const float*)d_in[10];
    const float* bih_m = (const float*)d_in[11];
    const float* bhh_m = (const float*)d_in[12];
    const float* Wa    = (const float*)d_in[13];
    const float* ba    = (const float*)d_in[14];
    float* out = (float*)d_out;

    int nrows = in_sizes[0] / 18;
    int block = 256;
    int grid = (nrows + block - 1) / block;

    if (ws_size >= W_TOT * sizeof(float)) {
        float* ws = (float*)d_ws;
        pack_weights_kernel<<<1, 512, 0, stream>>>(
            Wj, bj, Wm, bm, Wih_j, Whh_j, bih_j, bhh_j,
            Wih_m, Whh_m, bih_m, bhh_m, Wa, ba, ws);
        aggreg_policy_packed<<<grid, block, 0, stream>>>(x, ws, out, nrows);
    } else {
        aggreg_policy_fallback<<<grid, block, 0, stream>>>(
            x, Wj, bj, Wm, bm, Wih_j, Whh_j, bih_j, bhh_j,
            Wih_m, Whh_m, bih_m, bhh_m, Wa, ba, out, nrows);
    }
}

// Round 3
// 139.687 us; speedup vs baseline: 1.8999x; 1.7089x over previous
//
#include <hip/hip_runtime.h>

// One thread = one row. Matmuls via v_dot2_f32_f16 (2 f16 MACs/instr, f32
// accum) with weights pre-packed+activation-scaled into d_ws as f16x2.
// State: f32 for the GRU update equation + packed f16x2 copies as dot2
// operands. Ping-pong A/B register state (no copy loop). Activations:
// sigmoid = rcp(1+exp2(pre)), tanh-part = 1-2*rcp(1+exp2(arg)), with the
// +-log2e scales folded into the packed weights/biases.

typedef _Float16 half2v __attribute__((ext_vector_type(2)));

__device__ __forceinline__ float fexp2(float x) { return __builtin_amdgcn_exp2f(x); }
__device__ __forceinline__ float frcp(float x)  { return __builtin_amdgcn_rcpf(x); }
__device__ __forceinline__ float fdot2(half2v a, half2v b, float c) {
    return __builtin_amdgcn_fdot2(a, b, c, false);
}
__device__ __forceinline__ half2v pkh(float a, float b) {
    return half2v{(_Float16)a, (_Float16)b};
}
__device__ __forceinline__ unsigned pku(float a, float b) {
    union { unsigned u; half2v h; } z; z.h = pkh(a, b); return z.u;
}
__device__ __forceinline__ half2v ldw(const unsigned* p, int i) {
    union { unsigned u; half2v h; } z; z.u = p[i]; return z.h;
}

// ---- ws layout ----
// u32 region (f16x2 pairs):
#define U_PJRZ 0    // [8][6] j rz rows: L01 L23 R01 R23 H01 H23, * -log2e
#define U_PJNLR 48  // [4][4] j inn rows: L01 L23 R01 R23, * 2log2e
#define U_PJNH 64   // [4][2] j hn rows: H01 H23, * 2log2e
#define U_PMRZ 72   // [8][4] m rz rows: I01 I23 H01 H23, * -log2e
#define U_PMNI 104  // [4][2] m inn rows: I01 I23, * 2log2e
#define U_PMNH 112  // [4][2] m hn rows: H01 H23, * 2log2e
// f32 region (indices in floats):
#define F_BRZJ 120  // [8] (bih_j+bhh_j)[0:8] * -log2e
#define F_BINJ 128  // [4] bih_j[8:12] * 2log2e
#define F_BHNJ 132  // [4] bhh_j[8:12] * 2log2e
#define F_BRZM 136  // [8]
#define F_BINM 144  // [4]
#define F_BHNM 148  // [4]
#define F_WJ   152  // [4][2]
#define F_BJ   160  // [4]
#define F_WM   164  // [4][4]
#define F_BM   180  // [4]
#define F_WA   184  // [4]
#define F_BA   188  // [1]
#define W_TOT2 189

__global__ void pack_weights2(
    const float* __restrict__ Wj,    const float* __restrict__ bj,
    const float* __restrict__ Wm,    const float* __restrict__ bm,
    const float* __restrict__ Wih_j, const float* __restrict__ Whh_j,
    const float* __restrict__ bih_j, const float* __restrict__ bhh_j,
    const float* __restrict__ Wih_m, const float* __restrict__ Whh_m,
    const float* __restrict__ bih_m, const float* __restrict__ bhh_m,
    const float* __restrict__ Wa,    const float* __restrict__ ba,
    void* __restrict__ wsv)
{
    unsigned* wu = (unsigned*)wsv;
    float*    wf = (float*)wsv;
    int t = threadIdx.x;
    const float SN = -1.44269504088896f;   // sigmoid scale: exp2(SN*x)=e^-x
    const float ST =  2.88539008177793f;   // tanh scale:    exp2(ST*x)=e^(2x)
    if (t < 48) {                                    // j rz pairs
        int g = t / 6, p = t % 6; float a, b;
        if (p < 4) { a = Wih_j[g*8 + 2*p];     b = Wih_j[g*8 + 2*p + 1]; }
        else       { a = Whh_j[g*4 + 2*(p-4)]; b = Whh_j[g*4 + 2*(p-4) + 1]; }
        wu[t] = pku(a * SN, b * SN);
    } else if (t < 64) {                             // j inn LR pairs
        int i = t - 48, u = i / 4, p = i % 4;
        wu[t] = pku(Wih_j[(8+u)*8 + 2*p] * ST, Wih_j[(8+u)*8 + 2*p + 1] * ST);
    } else if (t < 72) {                             // j hn H pairs
        int i = t - 64, u = i / 2, p = i % 2;
        wu[t] = pku(Whh_j[(8+u)*4 + 2*p] * ST, Whh_j[(8+u)*4 + 2*p + 1] * ST);
    } else if (t < 104) {                            // m rz pairs
        int i = t - 72, g = i / 4, p = i % 4; float a, b;
        if (p < 2) { a = Wih_m[g*4 + 2*p];     b = Wih_m[g*4 + 2*p + 1]; }
        else       { a = Whh_m[g*4 + 2*(p-2)]; b = Whh_m[g*4 + 2*(p-2) + 1]; }
        wu[t] = pku(a * SN, b * SN);
    } else if (t < 112) {                            // m inn pairs
        int i = t - 104, u = i / 2, p = i % 2;
        wu[t] = pku(Wih_m[(8+u)*4 + 2*p] * ST, Wih_m[(8+u)*4 + 2*p + 1] * ST);
    } else if (t < 120) {                            // m hn pairs
        int i = t - 112, u = i / 2, p = i % 2;
        wu[t] = pku(Whh_m[(8+u)*4 + 2*p] * ST, Whh_m[(8+u)*4 + 2*p + 1] * ST);
    } else if (t < 128) { wf[t] = (bih_j[t-120] + bhh_j[t-120]) * SN; }
    else if (t < 132)   { wf[t] = bih_j[8 + t - 128] * ST; }
    else if (t < 136)   { wf[t] = bhh_j[8 + t - 132] * ST; }
    else if (t < 144)   { wf[t] = (bih_m[t-136] + bhh_m[t-136]) * SN; }
    else if (t < 148)   { wf[t] = bih_m[8 + t - 144] * ST; }
    else if (t < 152)   { wf[t] = bhh_m[8 + t - 148] * ST; }
    else if (t < 160)   { wf[t] = Wj[t - 152]; }
    else if (t < 164)   { wf[t] = bj[t - 160]; }
    else if (t < 180)   { wf[t] = Wm[t - 164]; }
    else if (t < 184)   { wf[t] = bm[t - 180]; }
    else if (t < 188)   { wf[t] = Wa[t - 184]; }
    else if (t == 188)  { wf[t] = ba[0]; }
}

__global__ __launch_bounds__(256, 4) void aggreg_policy_dot2(
    const float* __restrict__ x, const void* __restrict__ wsv,
    float* __restrict__ out, int nrows)
{
    const unsigned* WU = (const unsigned*)wsv;
    const float*    WF = (const float*)wsv;
    int b = blockIdx.x * blockDim.x + threadIdx.x;
    if (b >= nrows) return;

    const float2* xr2 = (const float2*)(x + (long)b * 18);
    float xin[18];
    #pragma unroll
    for (int i = 0; i < 9; ++i) { float2 v = xr2[i]; xin[2*i] = v.x; xin[2*i+1] = v.y; }

    float hjA[7][4], hmA[4], hjB[7][4], hmB[4];
    half2v pjA[7][2], pmA[2], pjB[7][2], pmB[2];

    #pragma unroll
    for (int k = 0; k < 7; ++k) {
        #pragma unroll
        for (int u = 0; u < 4; ++u)
            hjA[k][u] = fmaf(WF[F_WJ + u*2], xin[4 + k],
                        fmaf(WF[F_WJ + u*2 + 1], xin[11 + k], WF[F_BJ + u]));
        pjA[k][0] = pkh(hjA[k][0], hjA[k][1]);
        pjA[k][1] = pkh(hjA[k][2], hjA[k][3]);
    }
    #pragma unroll
    for (int u = 0; u < 4; ++u) {
        float a = WF[F_BM + u];
        #pragma unroll
        for (int v = 0; v < 4; ++v) a = fmaf(WF[F_WM + u*4 + v], xin[v], a);
        hmA[u] = a;
    }
    pmA[0] = pkh(hmA[0], hmA[1]);
    pmA[1] = pkh(hmA[2], hmA[3]);

    auto step = [&](const float (&shj)[7][4], const float (&shm)[4],
                    const half2v (&spj)[7][2], const half2v (&spm)[2],
                    float (&dhj)[7][4], float (&dhm)[4],
                    half2v (&dpj)[7][2], half2v (&dpm)[2]) {
        // ---- m-GRU: input = hj[0], hidden = hm (both OLD) ----
        {
            float pre[8], inn[4], hn[4];
            #pragma unroll
            for (int g = 0; g < 8; ++g) {
                float a = WF[F_BRZM + g];
                a = fdot2(spj[0][0], ldw(WU, U_PMRZ + g*4 + 0), a);
                a = fdot2(spj[0][1], ldw(WU, U_PMRZ + g*4 + 1), a);
                a = fdot2(spm[0],    ldw(WU, U_PMRZ + g*4 + 2), a);
                a = fdot2(spm[1],    ldw(WU, U_PMRZ + g*4 + 3), a);
                pre[g] = a;
            }
            #pragma unroll
            for (int u = 0; u < 4; ++u) {
                float a = WF[F_BINM + u];
                a = fdot2(spj[0][0], ldw(WU, U_PMNI + u*2 + 0), a);
                a = fdot2(spj[0][1], ldw(WU, U_PMNI + u*2 + 1), a);
                inn[u] = a;
                float c = WF[F_BHNM + u];
                c = fdot2(spm[0], ldw(WU, U_PMNH + u*2 + 0), c);
                c = fdot2(spm[1], ldw(WU, U_PMNH + u*2 + 1), c);
                hn[u] = c;
            }
            #pragma unroll
            for (int u = 0; u < 4; ++u) {
                float r = frcp(1.0f + fexp2(pre[u]));
                float z = frcp(1.0f + fexp2(pre[4 + u]));
                float narg = fmaf(r, hn[u], inn[u]);
                float n = fmaf(-2.0f, frcp(1.0f + fexp2(narg)), 1.0f);
                dhm[u] = fmaf(z, shm[u] - n, n);
            }
            dpm[0] = pkh(dhm[0], dhm[1]);
            dpm[1] = pkh(dhm[2], dhm[3]);
        }
        // ---- j-GRU over 7 nodes (all read OLD state) ----
        #pragma unroll
        for (int k = 0; k < 7; ++k) {
            half2v L0 = (k == 0) ? spm[0] : spj[k-1][0];
            half2v L1 = (k == 0) ? spm[1] : spj[k-1][1];
            half2v H0 = spj[k][0], H1 = spj[k][1];
            float pre[8], inn[4], hn[4];
            #pragma unroll
            for (int g = 0; g < 8; ++g) {
                float a = WF[F_BRZJ + g];
                a = fdot2(L0, ldw(WU, U_PJRZ + g*6 + 0), a);
                a = fdot2(L1, ldw(WU, U_PJRZ + g*6 + 1), a);
                if (k != 6) {   // right neighbor of last cell is zero-pad
                    a = fdot2(spj[k+1][0], ldw(WU, U_PJRZ + g*6 + 2), a);
                    a = fdot2(spj[k+1][1], ldw(WU, U_PJRZ + g*6 + 3), a);
                }
                a = fdot2(H0, ldw(WU, U_PJRZ + g*6 + 4), a);
                a = fdot2(H1, ldw(WU, U_PJRZ + g*6 + 5), a);
                pre[g] = a;
            }
            #pragma unroll
            for (int u = 0; u < 4; ++u) {
                float a = WF[F_BINJ + u];
                a = fdot2(L0, ldw(WU, U_PJNLR + u*4 + 0), a);
                a = fdot2(L1, ldw(WU, U_PJNLR + u*4 + 1), a);
                if (k != 6) {
                    a = fdot2(spj[k+1][0], ldw(WU, U_PJNLR + u*4 + 2), a);
                    a = fdot2(spj[k+1][1], ldw(WU, U_PJNLR + u*4 + 3), a);
                }
                inn[u] = a;
                float c = WF[F_BHNJ + u];
                c = fdot2(H0, ldw(WU, U_PJNH + u*2 + 0), c);
                c = fdot2(H1, ldw(WU, U_PJNH + u*2 + 1), c);
                hn[u] = c;
            }
            float n0, n1, n2, n3;
            #pragma unroll
            for (int u = 0; u < 4; ++u) {
                float r = frcp(1.0f + fexp2(pre[u]));
                float z = frcp(1.0f + fexp2(pre[4 + u]));
                float narg = fmaf(r, hn[u], inn[u]);
                float n = fmaf(-2.0f, frcp(1.0f + fexp2(narg)), 1.0f);
                float h = fmaf(z, shj[k][u] - n, n);
                dhj[k][u] = h;
                if (u == 0) n0 = h; else if (u == 1) n1 = h;
                else if (u == 2) n2 = h; else n3 = h;
            }
            dpj[k][0] = pkh(n0, n1);
            dpj[k][1] = pkh(n2, n3);
        }
    };

    // 7 iterations: 3 x (A->B, B->A) + final A->B; result in B.
    #pragma unroll 1
    for (int d = 0; d < 3; ++d) {
        step(hjA, hmA, pjA, pmA, hjB, hmB, pjB, pmB);
        step(hjB, hmB, pjB, pmB, hjA, hmA, pjA, pmA);
    }
    step(hjA, hmA, pjA, pmA, hjB, hmB, pjB, pmB);

    float* orow = out + (long)b * 7;
    #pragma unroll
    for (int k = 0; k < 7; ++k) {
        float a = WF[F_BA];
        #pragma unroll
        for (int u = 0; u < 4; ++u) a = fmaf(WF[F_WA + u], hjB[k][u], a);
        orow[k] = a;
    }
}

// ---------------- f32 fallback (only if ws too small; never expected) --------
__device__ __forceinline__ float sigmoid_f(float x) {
    return frcp(1.0f + fexp2(-1.44269504088896f * x));
}
__device__ __forceinline__ float tanh_f(float x) {
    float e = fexp2(2.88539008177793f * x);
    return 1.0f - 2.0f * frcp(1.0f + e);
}

__global__ __launch_bounds__(256) void aggreg_policy_fallback(
    const float* __restrict__ x,
    const float* __restrict__ Wj,    const float* __restrict__ bj,
    const float* __restrict__ Wm,    const float* __restrict__ bm,
    const float* __restrict__ Wih_j, const float* __restrict__ Whh_j,
    const float* __restrict__ bih_j, const float* __restrict__ bhh_j,
    const float* __restrict__ Wih_m, const float* __restrict__ Whh_m,
    const float* __restrict__ bih_m, const float* __restrict__ bhh_m,
    const float* __restrict__ Wa,    const float* __restrict__ ba,
    float* __restrict__ out, int nrows)
{
    int b = blockIdx.x * blockDim.x + threadIdx.x;
    if (b >= nrows) return;
    const float* xr = x + (long)b * 18;
    float obs[4], jv[7], jd[7];
    #pragma unroll
    for (int i = 0; i < 4; ++i) obs[i] = xr[i];
    #pragma unroll
    for (int i = 0; i < 7; ++i) jv[i] = xr[4 + i];
    #pragma unroll
    for (int i = 0; i < 7; ++i) jd[i] = xr[11 + i];
    float hj[7][4], hm[4];
    #pragma unroll
    for (int k = 0; k < 7; ++k)
        #pragma unroll
        for (int u = 0; u < 4; ++u)
            hj[k][u] = fmaf(Wj[u*2], jv[k], fmaf(Wj[u*2+1], jd[k], bj[u]));
    #pragma unroll
    for (int u = 0; u < 4; ++u) {
        float a = bm[u];
        #pragma unroll
        for (int v = 0; v < 4; ++v) a = fmaf(Wm[u*4+v], obs[v], a);
        hm[u] = a;
    }
    float bmrz[8], bjrz[8];
    #pragma unroll
    for (int g = 0; g < 8; ++g) { bmrz[g] = bih_m[g]+bhh_m[g]; bjrz[g] = bih_j[g]+bhh_j[g]; }
    #pragma unroll 1
    for (int it = 0; it < 7; ++it) {
        float hmn[4];
        {
            float pre[8], inn[4], hn[4];
            #pragma unroll
            for (int g = 0; g < 8; ++g) {
                float a = bmrz[g];
                #pragma unroll
                for (int v = 0; v < 4; ++v) a = fmaf(Wih_m[g*4+v], hj[0][v], a);
                #pragma unroll
                for (int v = 0; v < 4; ++v) a = fmaf(Whh_m[g*4+v], hm[v], a);
                pre[g] = a;
            }
            #pragma unroll
            for (int u = 0; u < 4; ++u) {
                float a = bih_m[8+u];
                #pragma unroll
                for (int v = 0; v < 4; ++v) a = fmaf(Wih_m[(8+u)*4+v], hj[0][v], a);
                inn[u] = a;
                float c = bhh_m[8+u];
                #pragma unroll
                for (int v = 0; v < 4; ++v) c = fmaf(Whh_m[(8+u)*4+v], hm[v], c);
                hn[u] = c;
            }
            #pragma unroll
            for (int u = 0; u < 4; ++u) {
                float r = sigmoid_f(pre[u]);
                float z = sigmoid_f(pre[4+u]);
                float n = tanh_f(fmaf(r, hn[u], inn[u]));
                hmn[u] = fmaf(z, hm[u]-n, n);
            }
        }
        float nh[7][4];
        #pragma unroll
        for (int k = 0; k < 7; ++k) {
            float L[4], R[4];
            #pragma unroll
            for (int u = 0; u < 4; ++u) {
                L[u] = (k == 0) ? hm[u] : hj[k-1][u];
                R[u] = (k == 6) ? 0.0f  : hj[k+1][u];
            }
            float pre[8], inn[4], hn[4];
            #pragma unroll
            for (int g = 0; g < 8; ++g) {
                float a = bjrz[g];
                #pragma unroll
                for (int v = 0; v < 4; ++v) a = fmaf(Wih_j[g*8+v], L[v], a);
                #pragma unroll
                for (int v = 0; v < 4; ++v) a = fmaf(Wih_j[g*8+4+v], R[v], a);
                #pragma unroll
                for (int v = 0; v < 4; ++v) a = fmaf(Whh_j[g*4+v], hj[k][v], a);
                pre[g] = a;
            }
            #pragma unroll
            for (int u = 0; u < 4; ++u) {
                float a = bih_j[8+u];
                #pragma unroll
                for (int v = 0; v < 4; ++v) a = fmaf(Wih_j[(8+u)*8+v], L[v], a);
                #pragma unroll
                for (int v = 0; v < 4; ++v) a = fmaf(Wih_j[(8+u)*8+4+v], R[v], a);
                inn[u] = a;
                float c = bhh_j[8+u];
                #pragma unroll
                for (int v = 0; v < 4; ++v) c = fmaf(Whh_j[(8+u)*4+v], hj[k][v], c);
                hn[u] = c;
            }
            #pragma unroll
            for (int u = 0; u < 4; ++u) {
                float r = sigmoid_f(pre[u]);
                float z = sigmoid_f(pre[4+u]);
                float n = tanh_f(fmaf(r, hn[u], inn[u]));
                nh[k][u] = fmaf(z, hj[k][u]-n, n);
            }
        }
        #pragma unroll
        for (int k = 0; k < 7; ++k)
            #pragma unroll
            for (int u = 0; u < 4; ++u) hj[k][u] = nh[k][u];
        #pragma unroll
        for (int u = 0; u < 4; ++u) hm[u] = hmn[u];
    }
    float* orow = out + (long)b * 7;
    #pragma unroll
    for (int k = 0; k < 7; ++k) {
        float a = ba[0];
        #pragma unroll
        for (int u = 0; u < 4; ++u) a = fmaf(Wa[u], hj[k][u], a);
        orow[k] = a;
    }
}

extern "C" void kernel_launch(void* const* d_in, const int* in_sizes, int n_in,
                              void* d_out, int out_size, void* d_ws, size_t ws_size,
                              hipStream_t stream) {
    const float* x     = (const float*)d_in[0];
    const float* Wj    = (const float*)d_in[1];
    const float* bj    = (const float*)d_in[2];
    const float* Wm    = (const float*)d_in[3];
    const float* bm    = (const float*)d_in[4];
    const float* Wih_j = (const float*)d_in[5];
    const float* Whh_j = (const float*)d_in[6];
    const float* bih_j = (const float*)d_in[7];
    const float* bhh_j = (const float*)d_in[8];
    const float* Wih_m = (const float*)d_in[9];
    const float* Whh_m = (const float*)d_in[10];
    const float* bih_m = (const float*)d_in[11];
    const float* bhh_m = (const float*)d_in[12];
    const float* Wa    = (const float*)d_in[13];
    const float* ba    = (const float*)d_in[14];
    float* out = (float*)d_out;

    int nrows = in_sizes[0] / 18;
    int block = 256;
    int grid = (nrows + block - 1) / block;

    if (ws_size >= W_TOT2 * sizeof(float)) {
        pack_weights2<<<1, 256, 0, stream>>>(
            Wj, bj, Wm, bm, Wih_j, Whh_j, bih_j, bhh_j,
            Wih_m, Whh_m, bih_m, bhh_m, Wa, ba, d_ws);
        aggreg_policy_dot2<<<grid, block, 0, stream>>>(x, d_ws, out, nrows);
    } else {
        aggreg_policy_fallback<<<grid, block, 0, stream>>>(
            x, Wj, bj, Wm, bm, Wih_j, Whh_j, bih_j, bhh_j,
            Wih_m, Whh_m, bih_m, bhh_m, Wa, ba, out, nrows);
    }
}